// Round 11
// baseline (1089.519 us; speedup 1.0000x reference)
//
#include <hip/hip_runtime.h>
#include <hip/hip_bf16.h>

// Two-pass scheme (semantics = R9-certified HD ordering):
//   PASS 1 (bulk): D ~= X @ sign(W) via bf16 MFMA, 2-plane Dekker split
//     x = h1 + h2 (bf16 RNE planes; residual ~2^-17|x|), signs exact in bf16.
//     Virtual K = 2*2048: k-tiles 0..31 = plane h1, 32..63 = plane h2,
//     all accumulated into the same f32 MFMA accumulator.
//     Write sign(D) to O. Where |D| < TAU, append index to ws flag list
//     (bulk error rms ~1.5e-4; TAU=6e-3 = >20 sigma covers every element
//     whose sign is f32-ordering-contested, margin certified by R7/R9).
//   PASS 2 (fixup): recompute flagged elements (~1800) with the EXACT
//     HD chain: OpenBLAS Q=384 plain-tail panels [384x5,128], ascending-k
//     f32 fmaf, sum += part per panel (bit-identical to R9's pass).

typedef __bf16 bf16x8 __attribute__((ext_vector_type(8)));
typedef float f32x4 __attribute__((ext_vector_type(4)));

#define TAU 6e-3f

__device__ __forceinline__ float sgnf(float v) {
    return (v > 0.f) ? 1.f : ((v < 0.f) ? -1.f : 0.f);
}
__device__ __forceinline__ ushort f2bf(float x) {            // f32->bf16 RNE
    uint u = __float_as_uint(x);
    u += 0x7FFFu + ((u >> 16) & 1u);
    return (ushort)(u >> 16);
}
__device__ __forceinline__ float bf2f(ushort h) {
    return __uint_as_float(((uint)h) << 16);
}
__device__ __forceinline__ ushort sgnbf(float w) {           // sign as bf16
    return (w > 0.f) ? (ushort)0x3F80 : ((w < 0.f) ? (ushort)0xBF80 : (ushort)0);
}

__global__ __launch_bounds__(256, 2)
void bulk_mfma(const float* __restrict__ X,   // [M][K] f32
               const float* __restrict__ W,   // [K][N] f32
               float* __restrict__ O,         // [M][N] f32
               uint* __restrict__ flags,      // [0]=count, [1..]=indices
               uint cap, int M, int N, int K)
{
    __shared__ __align__(16) char sA[128 * 128];  // 128 rows x 64 bf16, XOR-swizzled
    __shared__ __align__(16) char sB[128 * 128];  // 128 n-rows x 64 bf16

    const int tid = threadIdx.x;
    const int l   = tid & 63;
    const int w   = tid >> 6;
    const int wr  = w >> 1, wc = w & 1;   // 2x2 waves, 64x64 each
    const int lr  = l & 15;               // frag row/col lane
    const int lk  = l >> 4;               // k-group 0..3

    const int m0 = blockIdx.y * 128;
    const int n0 = blockIdx.x * 128;

    f32x4 acc[4][4];
    #pragma unroll
    for (int i = 0; i < 4; ++i)
        #pragma unroll
        for (int j = 0; j < 4; ++j)
            acc[i][j] = (f32x4){0.f, 0.f, 0.f, 0.f};

    const int NT = K / 64;                 // 32 real k-tiles per plane

    for (int kt = 0; kt < 2 * NT; ++kt) {
        const int plane = (kt >= NT);
        const int kr0 = (plane ? (kt - NT) : kt) * 64;

        // ---- stage A: 128 rows x 64 k, f32 -> bf16 plane, b128 writes ----
        #pragma unroll
        for (int h = 0; h < 4; ++h) {
            const int idx = tid + 256 * h;        // 0..1023
            const int r   = idx >> 3;             // 0..127
            const int c8  = (idx & 7) * 8;        // 0..56
            const float* xp = &X[(size_t)(m0 + r) * K + kr0 + c8];
            const float4 v0 = *(const float4*)xp;
            const float4 v1 = *(const float4*)(xp + 4);
            const float xs[8] = {v0.x, v0.y, v0.z, v0.w, v1.x, v1.y, v1.z, v1.w};
            ushort hb[8];
            if (!plane) {
                #pragma unroll
                for (int e = 0; e < 8; ++e) hb[e] = f2bf(xs[e]);
            } else {
                #pragma unroll
                for (int e = 0; e < 8; ++e) {
                    const ushort h1 = f2bf(xs[e]);
                    hb[e] = f2bf(xs[e] - bf2f(h1));   // exact residual (Sterbenz)
                }
            }
            uint4 pk;
            pk.x = (uint)hb[0] | ((uint)hb[1] << 16);
            pk.y = (uint)hb[2] | ((uint)hb[3] << 16);
            pk.z = (uint)hb[4] | ((uint)hb[5] << 16);
            pk.w = (uint)hb[6] | ((uint)hb[7] << 16);
            *(uint4*)(sA + r * 128 + ((c8 * 2) ^ ((r & 7) << 4))) = pk;
        }

        // ---- stage B: sign(W) transposed to [n][k], b128 writes ----
        {
            const int ko = (tid >> 5) * 8;        // 0..56 (k-oct)
            const int n4 = (tid & 31) * 4;        // 0..124
            float4 rv[8];
            #pragma unroll
            for (int j = 0; j < 8; ++j)
                rv[j] = *(const float4*)&W[(size_t)(kr0 + ko + j) * N + n0 + n4];
            #pragma unroll
            for (int c = 0; c < 4; ++c) {
                ushort sb[8];
                #pragma unroll
                for (int j = 0; j < 8; ++j)
                    sb[j] = sgnbf(((const float*)&rv[j])[c]);
                uint4 pk;
                pk.x = (uint)sb[0] | ((uint)sb[1] << 16);
                pk.y = (uint)sb[2] | ((uint)sb[3] << 16);
                pk.z = (uint)sb[4] | ((uint)sb[5] << 16);
                pk.w = (uint)sb[6] | ((uint)sb[7] << 16);
                const int row = n4 + c;
                *(uint4*)(sB + row * 128 + ((ko * 2) ^ ((row & 7) << 4))) = pk;
            }
        }
        __syncthreads();

        // ---- MFMA: 2 x (K=32) x 16 fragments ----
        #pragma unroll
        for (int kk = 0; kk < 2; ++kk) {
            const int kb = kk * 64 + lk * 16;     // byte offset along k
            bf16x8 af[4], bg[4];
            #pragma unroll
            for (int i = 0; i < 4; ++i) {
                const int row = wr * 64 + i * 16 + lr;
                af[i] = *(const bf16x8*)(sA + row * 128 + (kb ^ ((row & 7) << 4)));
            }
            #pragma unroll
            for (int j = 0; j < 4; ++j) {
                const int row = wc * 64 + j * 16 + lr;
                bg[j] = *(const bf16x8*)(sB + row * 128 + (kb ^ ((row & 7) << 4)));
            }
            #pragma unroll
            for (int i = 0; i < 4; ++i)
                #pragma unroll
                for (int j = 0; j < 4; ++j)
                    acc[i][j] = __builtin_amdgcn_mfma_f32_16x16x32_bf16(
                        af[i], bg[j], acc[i][j], 0, 0, 0);
        }
        __syncthreads();
    }

    // ---- epilogue: sign + borderline flagging ----
    // C/D map (m89-verified): col = lane&15, row = (lane>>4)*4 + reg
    #pragma unroll
    for (int i = 0; i < 4; ++i) {
        #pragma unroll
        for (int j = 0; j < 4; ++j) {
            #pragma unroll
            for (int q = 0; q < 4; ++q) {
                const int m = m0 + wr * 64 + i * 16 + lk * 4 + q;
                const int n = n0 + wc * 64 + j * 16 + lr;
                const float d = acc[i][j][q];
                const size_t oi = (size_t)m * N + n;
                O[oi] = sgnf(d);
                if (fabsf(d) < TAU) {
                    const uint pos = atomicAdd(flags, 1u);
                    if (pos < cap) flags[1 + pos] = (uint)oi;
                }
            }
        }
    }
}

__global__ __launch_bounds__(256)
void fixup_exact(const float* __restrict__ X, const float* __restrict__ W,
                 float* __restrict__ O, const uint* __restrict__ flags,
                 uint cap, int K, int N)
{
    uint count = flags[0];
    if (count > cap) count = cap;
    for (uint t = blockIdx.x * blockDim.x + threadIdx.x; t < count;
         t += gridDim.x * blockDim.x) {
        const uint idx = flags[1 + t];
        const int n = (int)(idx % (uint)N);
        const float* xrow = X + (size_t)(idx / (uint)N) * K;
        const float* wcol = W + n;
        float sum = 0.f;
        int ls = 0;
        while (ls < K) {                      // HD: Q=384 plain tail [384x5,128]
            const int ke = (ls + 384 < K) ? (ls + 384) : K;
            float part = 0.f;
            for (int k = ls; k < ke; ++k)
                part = fmaf(xrow[k], sgnf(wcol[(size_t)k * N]), part);
            sum += part;
            ls = ke;
        }
        O[idx] = sgnf(sum);
    }
}

extern "C" void kernel_launch(void* const* d_in, const int* in_sizes, int n_in,
                              void* d_out, int out_size, void* d_ws, size_t ws_size,
                              hipStream_t stream) {
    // order-robust input binding (x = larger buffer)
    const float* X;
    const float* W;
    long long wsize;
    if ((long long)in_sizes[0] >= (long long)in_sizes[1]) {
        X = (const float*)d_in[0];
        W = (const float*)d_in[1]; wsize = in_sizes[1];
    } else {
        X = (const float*)d_in[1];
        W = (const float*)d_in[0]; wsize = in_sizes[0];
    }
    float* O = (float*)d_out;

    int K = 1;
    while ((long long)K * K < wsize) ++K;        // K = 2048
    const int N = K;
    const int M = (int)((long long)out_size / N);

    uint* flags = (uint*)d_ws;
    uint cap = 0;
    if (ws_size >= 8) {
        unsigned long long c = (unsigned long long)(ws_size / 4) - 1ull;
        cap = (uint)((c > 0x00FFFFFFull) ? 0x00FFFFFFull : c);
    }

    hipMemsetAsync(d_ws, 0, 4, stream);          // reset flag counter
    dim3 grid(N / 128, M / 128);
    bulk_mfma<<<grid, 256, 0, stream>>>(X, W, O, flags, cap, M, N, K);
    fixup_exact<<<64, 256, 0, stream>>>(X, W, O, flags, cap, K, N);
}

// Round 12
// 527.102 us; speedup vs baseline: 2.0670x; 2.0670x over previous
//
#include <hip/hip_runtime.h>
#include <hip/hip_bf16.h>

// Two-pass scheme (semantics = R9-certified HD ordering):
//   PASS 1 (bulk): D ~= X @ sign(W) via bf16 MFMA, 2-plane Dekker split.
//     Write sign(D); flag |D| < TAU into ws list (bulk err rms ~1.5e-4,
//     TAU = 6e-3 = >20 sigma; every f32-ordering-contested element flagged).
//   PASS 2 (fixup): WAVE-COOPERATIVE exact recompute of flagged elements:
//     64 lanes gather p[k] = x[k]*sign(w[k][n]) into LDS (parallel strided
//     loads, latency overlapped), lane 0 replays the exact HD chain
//     (Q=384 plain tail [384x5,128], ascending-k; staged exact products +
//     sequential f32 adds == fmaf chain bit-for-bit).
// R11 lesson: per-thread fixup was latency-bound (700 us, occ 0.3%).

typedef __bf16 bf16x8 __attribute__((ext_vector_type(8)));
typedef float f32x4 __attribute__((ext_vector_type(4)));

#define TAU 6e-3f

__device__ __forceinline__ float sgnf(float v) {
    return (v > 0.f) ? 1.f : ((v < 0.f) ? -1.f : 0.f);
}
__device__ __forceinline__ ushort f2bf(float x) {            // f32->bf16 RNE
    uint u = __float_as_uint(x);
    u += 0x7FFFu + ((u >> 16) & 1u);
    return (ushort)(u >> 16);
}
__device__ __forceinline__ float bf2f(ushort h) {
    return __uint_as_float(((uint)h) << 16);
}
__device__ __forceinline__ ushort sgnbf(float w) {           // sign as bf16
    return (w > 0.f) ? (ushort)0x3F80 : ((w < 0.f) ? (ushort)0xBF80 : (ushort)0);
}

__global__ __launch_bounds__(256, 2)
void bulk_mfma(const float* __restrict__ X,   // [M][K] f32
               const float* __restrict__ W,   // [K][N] f32
               float* __restrict__ O,         // [M][N] f32
               uint* __restrict__ flags,      // [0]=count, [1..]=indices
               uint cap, int M, int N, int K)
{
    __shared__ __align__(16) char sA[128 * 128];  // 128 rows x 64 bf16, XOR-swizzled
    __shared__ __align__(16) char sB[128 * 128];  // 128 n-rows x 64 bf16

    const int tid = threadIdx.x;
    const int l   = tid & 63;
    const int w   = tid >> 6;
    const int wr  = w >> 1, wc = w & 1;   // 2x2 waves, 64x64 each
    const int lr  = l & 15;               // frag row/col lane
    const int lk  = l >> 4;               // k-group 0..3

    const int m0 = blockIdx.y * 128;
    const int n0 = blockIdx.x * 128;

    f32x4 acc[4][4];
    #pragma unroll
    for (int i = 0; i < 4; ++i)
        #pragma unroll
        for (int j = 0; j < 4; ++j)
            acc[i][j] = (f32x4){0.f, 0.f, 0.f, 0.f};

    const int NT = K / 64;                 // 32 real k-tiles per plane

    for (int kt = 0; kt < 2 * NT; ++kt) {
        const int plane = (kt >= NT);
        const int kr0 = (plane ? (kt - NT) : kt) * 64;

        // ---- stage A: 128 rows x 64 k, f32 -> bf16 plane, b128 writes ----
        #pragma unroll
        for (int h = 0; h < 4; ++h) {
            const int idx = tid + 256 * h;        // 0..1023
            const int r   = idx >> 3;             // 0..127
            const int c8  = (idx & 7) * 8;        // 0..56
            const float* xp = &X[(size_t)(m0 + r) * K + kr0 + c8];
            const float4 v0 = *(const float4*)xp;
            const float4 v1 = *(const float4*)(xp + 4);
            const float xs[8] = {v0.x, v0.y, v0.z, v0.w, v1.x, v1.y, v1.z, v1.w};
            ushort hb[8];
            if (!plane) {
                #pragma unroll
                for (int e = 0; e < 8; ++e) hb[e] = f2bf(xs[e]);
            } else {
                #pragma unroll
                for (int e = 0; e < 8; ++e) {
                    const ushort h1 = f2bf(xs[e]);
                    hb[e] = f2bf(xs[e] - bf2f(h1));   // exact residual
                }
            }
            uint4 pk;
            pk.x = (uint)hb[0] | ((uint)hb[1] << 16);
            pk.y = (uint)hb[2] | ((uint)hb[3] << 16);
            pk.z = (uint)hb[4] | ((uint)hb[5] << 16);
            pk.w = (uint)hb[6] | ((uint)hb[7] << 16);
            *(uint4*)(sA + r * 128 + ((c8 * 2) ^ ((r & 7) << 4))) = pk;
        }

        // ---- stage B: sign(W) transposed to [n][k], b128 writes ----
        {
            const int ko = (tid >> 5) * 8;        // 0..56 (k-oct)
            const int n4 = (tid & 31) * 4;        // 0..124
            float4 rv[8];
            #pragma unroll
            for (int j = 0; j < 8; ++j)
                rv[j] = *(const float4*)&W[(size_t)(kr0 + ko + j) * N + n0 + n4];
            #pragma unroll
            for (int c = 0; c < 4; ++c) {
                ushort sb[8];
                #pragma unroll
                for (int j = 0; j < 8; ++j)
                    sb[j] = sgnbf(((const float*)&rv[j])[c]);
                uint4 pk;
                pk.x = (uint)sb[0] | ((uint)sb[1] << 16);
                pk.y = (uint)sb[2] | ((uint)sb[3] << 16);
                pk.z = (uint)sb[4] | ((uint)sb[5] << 16);
                pk.w = (uint)sb[6] | ((uint)sb[7] << 16);
                const int row = n4 + c;
                *(uint4*)(sB + row * 128 + ((ko * 2) ^ ((row & 7) << 4))) = pk;
            }
        }
        __syncthreads();

        // ---- MFMA: 2 x (K=32) x 16 fragments ----
        #pragma unroll
        for (int kk = 0; kk < 2; ++kk) {
            const int kb = kk * 64 + lk * 16;     // byte offset along k
            bf16x8 af[4], bg[4];
            #pragma unroll
            for (int i = 0; i < 4; ++i) {
                const int row = wr * 64 + i * 16 + lr;
                af[i] = *(const bf16x8*)(sA + row * 128 + (kb ^ ((row & 7) << 4)));
            }
            #pragma unroll
            for (int j = 0; j < 4; ++j) {
                const int row = wc * 64 + j * 16 + lr;
                bg[j] = *(const bf16x8*)(sB + row * 128 + (kb ^ ((row & 7) << 4)));
            }
            #pragma unroll
            for (int i = 0; i < 4; ++i)
                #pragma unroll
                for (int j = 0; j < 4; ++j)
                    acc[i][j] = __builtin_amdgcn_mfma_f32_16x16x32_bf16(
                        af[i], bg[j], acc[i][j], 0, 0, 0);
        }
        __syncthreads();
    }

    // ---- epilogue: sign + borderline flagging ----
    #pragma unroll
    for (int i = 0; i < 4; ++i) {
        #pragma unroll
        for (int j = 0; j < 4; ++j) {
            #pragma unroll
            for (int q = 0; q < 4; ++q) {
                const int m = m0 + wr * 64 + i * 16 + lk * 4 + q;
                const int n = n0 + wc * 64 + j * 16 + lr;
                const float d = acc[i][j][q];
                const size_t oi = (size_t)m * N + n;
                O[oi] = sgnf(d);
                if (fabsf(d) < TAU) {
                    const uint pos = atomicAdd(flags, 1u);
                    if (pos < cap) flags[1 + pos] = (uint)oi;
                }
            }
        }
    }
}

// Wave-cooperative exact fixup: one 64-lane wave per flagged element.
__global__ __launch_bounds__(64)
void fixup_exact_wave(const float* __restrict__ X, const float* __restrict__ W,
                      float* __restrict__ O, const uint* __restrict__ flags,
                      uint cap, int K, int N)
{
    __shared__ float p[2048];   // staged exact products x[k]*s[k]

    uint count = flags[0];
    if (count > cap) count = cap;

    for (uint t = blockIdx.x; t < count; t += gridDim.x) {
        const uint idx = flags[1 + t];
        const int n = (int)(idx % (uint)N);
        const float* xrow = X + (size_t)(idx / (uint)N) * K;
        const float* wcol = W + n;

        if (K <= 2048) {
            // parallel gather: 64 lanes, strided column loads overlapped
            for (int k = threadIdx.x; k < K; k += 64)
                p[k] = xrow[k] * sgnf(wcol[(size_t)k * N]);
            __syncthreads();
            if (threadIdx.x == 0) {
                // exact HD chain: panels [384x5,128], ascending k.
                // (staged exact product + sequential f32 add == fmaf chain)
                float sum = 0.f;
                int ls = 0;
                while (ls < K) {
                    const int ke = (ls + 384 < K) ? (ls + 384) : K;
                    float part = 0.f;
                    for (int k = ls; k < ke; ++k) part += p[k];
                    sum += part;
                    ls = ke;
                }
                O[idx] = sgnf(sum);
            }
            __syncthreads();
        } else if (threadIdx.x == 0) {
            // fallback (not hit at K=2048): direct serial recompute
            float sum = 0.f;
            int ls = 0;
            while (ls < K) {
                const int ke = (ls + 384 < K) ? (ls + 384) : K;
                float part = 0.f;
                for (int k = ls; k < ke; ++k)
                    part = fmaf(xrow[k], sgnf(wcol[(size_t)k * N]), part);
                sum += part;
                ls = ke;
            }
            O[idx] = sgnf(sum);
        }
    }
}

extern "C" void kernel_launch(void* const* d_in, const int* in_sizes, int n_in,
                              void* d_out, int out_size, void* d_ws, size_t ws_size,
                              hipStream_t stream) {
    // order-robust input binding (x = larger buffer)
    const float* X;
    const float* W;
    long long wsize;
    if ((long long)in_sizes[0] >= (long long)in_sizes[1]) {
        X = (const float*)d_in[0];
        W = (const float*)d_in[1]; wsize = in_sizes[1];
    } else {
        X = (const float*)d_in[1];
        W = (const float*)d_in[0]; wsize = in_sizes[0];
    }
    float* O = (float*)d_out;

    int K = 1;
    while ((long long)K * K < wsize) ++K;        // K = 2048
    const int N = K;
    const int M = (int)((long long)out_size / N);

    uint* flags = (uint*)d_ws;
    uint cap = 0;
    if (ws_size >= 8) {
        unsigned long long c = (unsigned long long)(ws_size / 4) - 1ull;
        cap = (uint)((c > 0x00FFFFFFull) ? 0x00FFFFFFull : c);
    }

    hipMemsetAsync(d_ws, 0, 4, stream);          // reset flag counter
    dim3 grid(N / 128, M / 128);
    bulk_mfma<<<grid, 256, 0, stream>>>(X, W, O, flags, cap, M, N, K);
    fixup_exact_wave<<<2048, 64, 0, stream>>>(X, W, O, flags, cap, K, N);
}

// Round 13
// 314.774 us; speedup vs baseline: 3.4613x; 1.6745x over previous
//
#include <hip/hip_runtime.h>
#include <hip/hip_bf16.h>

// Three-phase scheme (semantics = R9-certified HD ordering):
//   PASS 0a: X f32 -> A2 [M][2K] bf16 (Dekker planes h1 | h2, exact residual)
//   PASS 0b: W f32 -> BT [N][K] bf16 sign, transposed (B^T layout for GEMM)
//   PASS 1:  bulk GEMM (bf16 MFMA, K_virtual = 2K, global_load_lds width-16,
//            XOR-swizzled via pre-swizzled SOURCE + swizzled READ, linear dest)
//            writes sign(D); flags |D| < TAU into ws list (TAU=6e-3 >> any
//            f32-ordering contest margin; validated R11/R12 absmax=0).
//   PASS 2:  wave-cooperative exact fixup (HD chain: OpenBLAS Q=384 plain
//            tail [384x5,128], ascending-k f32 adds of exact +-x products).
// Fallback (ws too small): R12's fused-conversion bulk kernel (certified).

typedef __bf16 bf16x8 __attribute__((ext_vector_type(8)));
typedef float f32x4 __attribute__((ext_vector_type(4)));

#define TAU 6e-3f

__device__ __forceinline__ float sgnf(float v) {
    return (v > 0.f) ? 1.f : ((v < 0.f) ? -1.f : 0.f);
}
__device__ __forceinline__ ushort f2bf(float x) {            // f32->bf16 RNE
    uint u = __float_as_uint(x);
    u += 0x7FFFu + ((u >> 16) & 1u);
    return (ushort)(u >> 16);
}
__device__ __forceinline__ float bf2f(ushort h) {
    return __uint_as_float(((uint)h) << 16);
}
__device__ __forceinline__ ushort sgnbf(float w) {           // sign as bf16
    return (w > 0.f) ? (ushort)0x3F80 : ((w < 0.f) ? (ushort)0xBF80 : (ushort)0);
}

// ---------------- PASS 0a: X -> Dekker bf16 planes ----------------
__global__ __launch_bounds__(256)
void conv_x_planes(const float* __restrict__ X, ushort* __restrict__ A2,
                   int M, int K)
{
    const long long t = (long long)blockIdx.x * 256 + threadIdx.x; // M*K/8
    const int perRow = K >> 3;
    const int m  = (int)(t / perRow);
    if (m >= M) return;
    const int j8 = (int)(t % perRow) * 8;

    const float4 v0 = *(const float4*)&X[(size_t)m * K + j8];
    const float4 v1 = *(const float4*)&X[(size_t)m * K + j8 + 4];
    const float xs[8] = {v0.x, v0.y, v0.z, v0.w, v1.x, v1.y, v1.z, v1.w};

    ushort h1[8], h2[8];
    #pragma unroll
    for (int e = 0; e < 8; ++e) {
        h1[e] = f2bf(xs[e]);
        h2[e] = f2bf(xs[e] - bf2f(h1[e]));   // Dekker residual (exact sub)
    }
    uint4 p1, p2;
    p1.x = (uint)h1[0] | ((uint)h1[1] << 16);
    p1.y = (uint)h1[2] | ((uint)h1[3] << 16);
    p1.z = (uint)h1[4] | ((uint)h1[5] << 16);
    p1.w = (uint)h1[6] | ((uint)h1[7] << 16);
    p2.x = (uint)h2[0] | ((uint)h2[1] << 16);
    p2.y = (uint)h2[2] | ((uint)h2[3] << 16);
    p2.z = (uint)h2[4] | ((uint)h2[5] << 16);
    p2.w = (uint)h2[6] | ((uint)h2[7] << 16);

    ushort* row = A2 + (size_t)m * 2 * K;
    *(uint4*)(row + j8)     = p1;   // plane 1 at [0, K)
    *(uint4*)(row + K + j8) = p2;   // plane 2 at [K, 2K)
}

// ---------------- PASS 0b: W -> sign(W)^T bf16 ----------------
__global__ __launch_bounds__(256)
void transp_sign(const float* __restrict__ W, ushort* __restrict__ BT,
                 int K, int N)
{
    __shared__ float tile[64][65];
    const int k0 = blockIdx.y * 64;
    const int n0 = blockIdx.x * 64;
    const int tr = threadIdx.x >> 6;    // 0..3
    const int tc = threadIdx.x & 63;

    #pragma unroll
    for (int h = 0; h < 16; ++h) {
        const int r = h * 4 + tr;
        tile[r][tc] = W[(size_t)(k0 + r) * N + n0 + tc];
    }
    __syncthreads();

    const int nr = threadIdx.x >> 2;        // 0..63  (n within tile)
    const int kc = (threadIdx.x & 3) * 16;  // 0,16,32,48 (k chunk)
    ushort sb[16];
    #pragma unroll
    for (int e = 0; e < 16; ++e) sb[e] = sgnbf(tile[kc + e][nr]);

    uint4 a, b;
    a.x = (uint)sb[0]  | ((uint)sb[1]  << 16);
    a.y = (uint)sb[2]  | ((uint)sb[3]  << 16);
    a.z = (uint)sb[4]  | ((uint)sb[5]  << 16);
    a.w = (uint)sb[6]  | ((uint)sb[7]  << 16);
    b.x = (uint)sb[8]  | ((uint)sb[9]  << 16);
    b.y = (uint)sb[10] | ((uint)sb[11] << 16);
    b.z = (uint)sb[12] | ((uint)sb[13] << 16);
    b.w = (uint)sb[14] | ((uint)sb[15] << 16);

    ushort* dst = BT + (size_t)(n0 + nr) * K + k0 + kc;
    *(uint4*)dst       = a;
    *(uint4*)(dst + 8) = b;
}

// ---------------- PASS 1: bulk GEMM (m97 structure) ----------------
__global__ __launch_bounds__(256)
void bulk_mfma_pre(const ushort* __restrict__ A2,   // [M][2K] bf16
                   const ushort* __restrict__ BT,   // [N][K]  bf16
                   float* __restrict__ O,
                   uint* __restrict__ flags, uint cap,
                   int M, int N, int K)             // K = real K (2048)
{
    __shared__ __align__(16) char sA[128 * 128];  // 128 rows x 64 bf16
    __shared__ __align__(16) char sB[128 * 128];

    const int tid = threadIdx.x;
    const int l   = tid & 63;
    const int w   = tid >> 6;
    const int wr  = w >> 1, wc = w & 1;
    const int lr  = l & 15;
    const int lk  = l >> 4;

    // bijective XCD swizzle (nwg % 8 == 0)
    const int nwg = gridDim.x;
    int wg = blockIdx.x;
    wg = (wg & 7) * (nwg >> 3) + (wg >> 3);
    const int nbx = N >> 7;
    const int m0 = (wg / nbx) * 128;
    const int n0 = (wg % nbx) * 128;

    f32x4 acc[4][4];
    #pragma unroll
    for (int i = 0; i < 4; ++i)
        #pragma unroll
        for (int j = 0; j < 4; ++j)
            acc[i][j] = (f32x4){0.f, 0.f, 0.f, 0.f};

    const int NTr = K >> 6;          // real k-tiles (32)
    const int NTv = 2 * NTr;         // virtual (64): A2 row is [h1|h2]
    const size_t rowA = (size_t)(2 * K) * 2;  // bytes per A2 row
    const size_t rowB = (size_t)K * 2;        // bytes per BT row
    const char* A2b = (const char*)A2;
    const char* BTb = (const char*)BT;

    for (int kt = 0; kt < NTv; ++kt) {
        const size_t kA = (size_t)kt * 128;            // byte offset in A2 row
        const size_t kB = (size_t)(kt % NTr) * 128;    // BT repeats per plane

        // stage A+B: global_load_lds width 16, linear LDS dest,
        // inverse-swizzled per-lane SOURCE (involution with read XOR)
        #pragma unroll
        for (int h = 0; h < 4; ++h) {
            const int chunk = (w * 4 + h) * 64 + l;
            const int row = chunk >> 3;
            const int b   = (chunk & 7) * 16;
            const int bs  = b ^ ((row & 7) << 4);
            const char* srcA = A2b + (size_t)(m0 + row) * rowA + kA + bs;
            char* dstA = sA + (size_t)((w * 4 + h) * 64) * 16;  // wave-uniform
            __builtin_amdgcn_global_load_lds(
                (const __attribute__((address_space(1))) void*)srcA,
                (__attribute__((address_space(3))) void*)dstA, 16, 0, 0);
            const char* srcB = BTb + (size_t)(n0 + row) * rowB + kB + bs;
            char* dstB = sB + (size_t)((w * 4 + h) * 64) * 16;
            __builtin_amdgcn_global_load_lds(
                (const __attribute__((address_space(1))) void*)srcB,
                (__attribute__((address_space(3))) void*)dstB, 16, 0, 0);
        }
        __syncthreads();   // drains vmcnt(0) before barrier

        #pragma unroll
        for (int ks = 0; ks < 2; ++ks) {
            const int kb = ks * 64 + lk * 16;
            bf16x8 af[4], bg[4];
            #pragma unroll
            for (int i = 0; i < 4; ++i) {
                const int row = wr * 64 + i * 16 + lr;
                af[i] = *(const bf16x8*)(sA + row * 128 + (kb ^ ((row & 7) << 4)));
            }
            #pragma unroll
            for (int j = 0; j < 4; ++j) {
                const int row = wc * 64 + j * 16 + lr;
                bg[j] = *(const bf16x8*)(sB + row * 128 + (kb ^ ((row & 7) << 4)));
            }
            #pragma unroll
            for (int i = 0; i < 4; ++i)
                #pragma unroll
                for (int j = 0; j < 4; ++j)
                    acc[i][j] = __builtin_amdgcn_mfma_f32_16x16x32_bf16(
                        af[i], bg[j], acc[i][j], 0, 0, 0);
        }
        __syncthreads();
    }

    // epilogue: sign + borderline flagging (C/D map: col=lane&15, row=lk*4+q)
    #pragma unroll
    for (int i = 0; i < 4; ++i) {
        #pragma unroll
        for (int j = 0; j < 4; ++j) {
            #pragma unroll
            for (int q = 0; q < 4; ++q) {
                const int m = m0 + wr * 64 + i * 16 + lk * 4 + q;
                const int n = n0 + wc * 64 + j * 16 + lr;
                const float d = acc[i][j][q];
                const size_t oi = (size_t)m * N + n;
                O[oi] = sgnf(d);
                if (fabsf(d) < TAU) {
                    const uint pos = atomicAdd(flags, 1u);
                    if (pos < cap) flags[1 + pos] = (uint)oi;
                }
            }
        }
    }
}

// ---------------- FALLBACK bulk (R12, fused conversion) ----------------
__global__ __launch_bounds__(256, 2)
void bulk_mfma_fb(const float* __restrict__ X, const float* __restrict__ W,
                  float* __restrict__ O, uint* __restrict__ flags,
                  uint cap, int M, int N, int K)
{
    __shared__ __align__(16) char sA[128 * 128];
    __shared__ __align__(16) char sB[128 * 128];

    const int tid = threadIdx.x;
    const int l   = tid & 63;
    const int w   = tid >> 6;
    const int wr  = w >> 1, wc = w & 1;
    const int lr  = l & 15;
    const int lk  = l >> 4;

    const int m0 = blockIdx.y * 128;
    const int n0 = blockIdx.x * 128;

    f32x4 acc[4][4];
    #pragma unroll
    for (int i = 0; i < 4; ++i)
        #pragma unroll
        for (int j = 0; j < 4; ++j)
            acc[i][j] = (f32x4){0.f, 0.f, 0.f, 0.f};

    const int NT = K / 64;

    for (int kt = 0; kt < 2 * NT; ++kt) {
        const int plane = (kt >= NT);
        const int kr0 = (plane ? (kt - NT) : kt) * 64;

        #pragma unroll
        for (int h = 0; h < 4; ++h) {
            const int idx = tid + 256 * h;
            const int r   = idx >> 3;
            const int c8  = (idx & 7) * 8;
            const float* xp = &X[(size_t)(m0 + r) * K + kr0 + c8];
            const float4 v0 = *(const float4*)xp;
            const float4 v1 = *(const float4*)(xp + 4);
            const float xs[8] = {v0.x, v0.y, v0.z, v0.w, v1.x, v1.y, v1.z, v1.w};
            ushort hb[8];
            if (!plane) {
                #pragma unroll
                for (int e = 0; e < 8; ++e) hb[e] = f2bf(xs[e]);
            } else {
                #pragma unroll
                for (int e = 0; e < 8; ++e) {
                    const ushort h1 = f2bf(xs[e]);
                    hb[e] = f2bf(xs[e] - bf2f(h1));
                }
            }
            uint4 pk;
            pk.x = (uint)hb[0] | ((uint)hb[1] << 16);
            pk.y = (uint)hb[2] | ((uint)hb[3] << 16);
            pk.z = (uint)hb[4] | ((uint)hb[5] << 16);
            pk.w = (uint)hb[6] | ((uint)hb[7] << 16);
            *(uint4*)(sA + r * 128 + ((c8 * 2) ^ ((r & 7) << 4))) = pk;
        }
        {
            const int ko = (tid >> 5) * 8;
            const int n4 = (tid & 31) * 4;
            float4 rv[8];
            #pragma unroll
            for (int j = 0; j < 8; ++j)
                rv[j] = *(const float4*)&W[(size_t)(kr0 + ko + j) * N + n0 + n4];
            #pragma unroll
            for (int c = 0; c < 4; ++c) {
                ushort sb[8];
                #pragma unroll
                for (int j = 0; j < 8; ++j)
                    sb[j] = sgnbf(((const float*)&rv[j])[c]);
                uint4 pk;
                pk.x = (uint)sb[0] | ((uint)sb[1] << 16);
                pk.y = (uint)sb[2] | ((uint)sb[3] << 16);
                pk.z = (uint)sb[4] | ((uint)sb[5] << 16);
                pk.w = (uint)sb[6] | ((uint)sb[7] << 16);
                const int row = n4 + c;
                *(uint4*)(sB + row * 128 + ((ko * 2) ^ ((row & 7) << 4))) = pk;
            }
        }
        __syncthreads();

        #pragma unroll
        for (int kk = 0; kk < 2; ++kk) {
            const int kb = kk * 64 + lk * 16;
            bf16x8 af[4], bg[4];
            #pragma unroll
            for (int i = 0; i < 4; ++i) {
                const int row = wr * 64 + i * 16 + lr;
                af[i] = *(const bf16x8*)(sA + row * 128 + (kb ^ ((row & 7) << 4)));
            }
            #pragma unroll
            for (int j = 0; j < 4; ++j) {
                const int row = wc * 64 + j * 16 + lr;
                bg[j] = *(const bf16x8*)(sB + row * 128 + (kb ^ ((row & 7) << 4)));
            }
            #pragma unroll
            for (int i = 0; i < 4; ++i)
                #pragma unroll
                for (int j = 0; j < 4; ++j)
                    acc[i][j] = __builtin_amdgcn_mfma_f32_16x16x32_bf16(
                        af[i], bg[j], acc[i][j], 0, 0, 0);
        }
        __syncthreads();
    }

    #pragma unroll
    for (int i = 0; i < 4; ++i) {
        #pragma unroll
        for (int j = 0; j < 4; ++j) {
            #pragma unroll
            for (int q = 0; q < 4; ++q) {
                const int m = m0 + wr * 64 + i * 16 + lk * 4 + q;
                const int n = n0 + wc * 64 + j * 16 + lr;
                const float d = acc[i][j][q];
                const size_t oi = (size_t)m * N + n;
                O[oi] = sgnf(d);
                if (fabsf(d) < TAU) {
                    const uint pos = atomicAdd(flags, 1u);
                    if (pos < cap) flags[1 + pos] = (uint)oi;
                }
            }
        }
    }
}

// ---------------- PASS 2: wave-cooperative exact fixup ----------------
__global__ __launch_bounds__(64)
void fixup_exact_wave(const float* __restrict__ X, const float* __restrict__ W,
                      float* __restrict__ O, const uint* __restrict__ flags,
                      uint cap, int K, int N)
{
    __shared__ float p[2048];

    uint count = flags[0];
    if (count > cap) count = cap;

    for (uint t = blockIdx.x; t < count; t += gridDim.x) {
        const uint idx = flags[1 + t];
        const int n = (int)(idx % (uint)N);
        const float* xrow = X + (size_t)(idx / (uint)N) * K;
        const float* wcol = W + n;

        if (K <= 2048) {
            for (int k = threadIdx.x; k < K; k += 64)
                p[k] = xrow[k] * sgnf(wcol[(size_t)k * N]);
            __syncthreads();
            if (threadIdx.x == 0) {
                float sum = 0.f;
                int ls = 0;
                while (ls < K) {                 // HD panels [384x5,128]
                    const int ke = (ls + 384 < K) ? (ls + 384) : K;
                    float part = 0.f;
                    for (int k = ls; k < ke; ++k) part += p[k];
                    sum += part;
                    ls = ke;
                }
                O[idx] = sgnf(sum);
            }
            __syncthreads();
        } else if (threadIdx.x == 0) {
            float sum = 0.f;
            int ls = 0;
            while (ls < K) {
                const int ke = (ls + 384 < K) ? (ls + 384) : K;
                float part = 0.f;
                for (int k = ls; k < ke; ++k)
                    part = fmaf(xrow[k], sgnf(wcol[(size_t)k * N]), part);
                sum += part;
                ls = ke;
            }
            O[idx] = sgnf(sum);
        }
    }
}

extern "C" void kernel_launch(void* const* d_in, const int* in_sizes, int n_in,
                              void* d_out, int out_size, void* d_ws, size_t ws_size,
                              hipStream_t stream) {
    // order-robust input binding (x = larger buffer)
    const float* X;
    const float* W;
    long long wsize;
    if ((long long)in_sizes[0] >= (long long)in_sizes[1]) {
        X = (const float*)d_in[0];
        W = (const float*)d_in[1]; wsize = in_sizes[1];
    } else {
        X = (const float*)d_in[1];
        W = (const float*)d_in[0]; wsize = in_sizes[0];
    }
    float* O = (float*)d_out;

    int K = 1;
    while ((long long)K * K < wsize) ++K;        // K = 2048
    const int N = K;
    const int M = (int)((long long)out_size / N);

    const size_t A2_BYTES = (size_t)M * 2 * K * 2;   // 64 MB
    const size_t BT_BYTES = (size_t)N * K * 2;       // 8 MB
    const size_t FLAG_OFF = A2_BYTES + BT_BYTES;
    const bool big_ws = (ws_size >= FLAG_OFF + (1u << 16)) &&
                        (M % 128 == 0) && (N % 128 == 0) && (K % 64 == 0);

    if (big_ws) {
        ushort* A2 = (ushort*)d_ws;
        ushort* BT = (ushort*)((char*)d_ws + A2_BYTES);
        uint* flags = (uint*)((char*)d_ws + FLAG_OFF);
        unsigned long long c = (unsigned long long)((ws_size - FLAG_OFF) / 4) - 1ull;
        const uint cap = (uint)((c > 0x00FFFFFFull) ? 0x00FFFFFFull : c);

        hipMemsetAsync(flags, 0, 4, stream);
        conv_x_planes<<<(M * (K >> 3) + 255) / 256, 256, 0, stream>>>(X, A2, M, K);
        dim3 tg(N / 64, K / 64);
        transp_sign<<<tg, 256, 0, stream>>>(W, BT, K, N);
        const int nwg = (N / 128) * (M / 128);       // 1024, % 8 == 0
        bulk_mfma_pre<<<nwg, 256, 0, stream>>>(A2, BT, O, flags, cap, M, N, K);
        fixup_exact_wave<<<2048, 64, 0, stream>>>(X, W, O, flags, cap, K, N);
    } else {
        uint* flags = (uint*)d_ws;
        uint cap = 0;
        if (ws_size >= 8) {
            unsigned long long c = (unsigned long long)(ws_size / 4) - 1ull;
            cap = (uint)((c > 0x00FFFFFFull) ? 0x00FFFFFFull : c);
        }
        hipMemsetAsync(d_ws, 0, 4, stream);
        dim3 grid(N / 128, M / 128);
        bulk_mfma_fb<<<grid, 256, 0, stream>>>(X, W, O, flags, cap, M, N, K);
        fixup_exact_wave<<<2048, 64, 0, stream>>>(X, W, O, flags, cap, K, N);
    }
}

// Round 14
// 245.842 us; speedup vs baseline: 4.4318x; 1.2804x over previous
//
#include <hip/hip_runtime.h>
#include <hip/hip_bf16.h>

// Three-phase scheme (semantics = R9-certified HD ordering):
//   PASS 0a: X f32 -> A2 [M][2K] bf16 (Dekker planes h1|h2); resets flag ctr.
//   PASS 0b: W f32 -> BT [N][K] bf16 sign, transposed.
//   PASS 1:  bulk GEMM 256x256 tile, BK=64, 8 waves, 128KB dbuf LDS,
//            raw s_barrier + COUNTED s_waitcnt vmcnt(8) (T3/T4: loads for
//            tile t+1 stay in flight across tile t's barriers).
//            Race-free ledger: prologue stages t0,t1 (16 loads/wave);
//            iter t: vmcnt(8) drains exactly tile t; barrier; compute;
//            barrier; stage t+2 into the buffer tile t just vacated.
//            Writes sign(D); flags |D| < TAU (=6e-3, >>20sigma of bulk err).
//   PASS 2:  wave-cooperative exact fixup reading BT (contiguous, coalesced);
//            HD chain: OpenBLAS Q=384 plain tail [384x5,128], ascending-k.
// Fallback (small ws / odd shapes): R12-certified fused bulk + W-column fixup.

typedef __bf16 bf16x8 __attribute__((ext_vector_type(8)));
typedef float f32x4 __attribute__((ext_vector_type(4)));

#define TAU 6e-3f

__device__ __forceinline__ float sgnf(float v) {
    return (v > 0.f) ? 1.f : ((v < 0.f) ? -1.f : 0.f);
}
__device__ __forceinline__ ushort f2bf(float x) {            // f32->bf16 RNE
    uint u = __float_as_uint(x);
    u += 0x7FFFu + ((u >> 16) & 1u);
    return (ushort)(u >> 16);
}
__device__ __forceinline__ float bf2f(ushort h) {
    return __uint_as_float(((uint)h) << 16);
}
__device__ __forceinline__ ushort sgnbf(float w) {           // sign as bf16
    return (w > 0.f) ? (ushort)0x3F80 : ((w < 0.f) ? (ushort)0xBF80 : (ushort)0);
}

// ---------------- PASS 0a: X -> Dekker bf16 planes (+ flag reset) ----------
__global__ __launch_bounds__(256)
void conv_x_planes(const float* __restrict__ X, ushort* __restrict__ A2,
                   uint* __restrict__ flags, int M, int K)
{
    if (blockIdx.x == 0 && threadIdx.x == 0) flags[0] = 0u;

    const long long t = (long long)blockIdx.x * 256 + threadIdx.x; // M*K/8
    const int perRow = K >> 3;
    const int m  = (int)(t / perRow);
    if (m >= M) return;
    const int j8 = (int)(t % perRow) * 8;

    const float4 v0 = *(const float4*)&X[(size_t)m * K + j8];
    const float4 v1 = *(const float4*)&X[(size_t)m * K + j8 + 4];
    const float xs[8] = {v0.x, v0.y, v0.z, v0.w, v1.x, v1.y, v1.z, v1.w};

    ushort h1[8], h2[8];
    #pragma unroll
    for (int e = 0; e < 8; ++e) {
        h1[e] = f2bf(xs[e]);
        h2[e] = f2bf(xs[e] - bf2f(h1[e]));   // Dekker residual (exact sub)
    }
    uint4 p1, p2;
    p1.x = (uint)h1[0] | ((uint)h1[1] << 16);
    p1.y = (uint)h1[2] | ((uint)h1[3] << 16);
    p1.z = (uint)h1[4] | ((uint)h1[5] << 16);
    p1.w = (uint)h1[6] | ((uint)h1[7] << 16);
    p2.x = (uint)h2[0] | ((uint)h2[1] << 16);
    p2.y = (uint)h2[2] | ((uint)h2[3] << 16);
    p2.z = (uint)h2[4] | ((uint)h2[5] << 16);
    p2.w = (uint)h2[6] | ((uint)h2[7] << 16);

    ushort* row = A2 + (size_t)m * 2 * K;
    *(uint4*)(row + j8)     = p1;
    *(uint4*)(row + K + j8) = p2;
}

// ---------------- PASS 0b: W -> sign(W)^T bf16 ----------------
__global__ __launch_bounds__(256)
void transp_sign(const float* __restrict__ W, ushort* __restrict__ BT,
                 int K, int N)
{
    __shared__ float tile[64][65];
    const int k0 = blockIdx.y * 64;
    const int n0 = blockIdx.x * 64;
    const int tr = threadIdx.x >> 6;
    const int tc = threadIdx.x & 63;

    #pragma unroll
    for (int h = 0; h < 16; ++h) {
        const int r = h * 4 + tr;
        tile[r][tc] = W[(size_t)(k0 + r) * N + n0 + tc];
    }
    __syncthreads();

    const int nr = threadIdx.x >> 2;
    const int kc = (threadIdx.x & 3) * 16;
    ushort sb[16];
    #pragma unroll
    for (int e = 0; e < 16; ++e) sb[e] = sgnbf(tile[kc + e][nr]);

    uint4 a, b;
    a.x = (uint)sb[0]  | ((uint)sb[1]  << 16);
    a.y = (uint)sb[2]  | ((uint)sb[3]  << 16);
    a.z = (uint)sb[4]  | ((uint)sb[5]  << 16);
    a.w = (uint)sb[6]  | ((uint)sb[7]  << 16);
    b.x = (uint)sb[8]  | ((uint)sb[9]  << 16);
    b.y = (uint)sb[10] | ((uint)sb[11] << 16);
    b.z = (uint)sb[12] | ((uint)sb[13] << 16);
    b.w = (uint)sb[14] | ((uint)sb[15] << 16);

    ushort* dst = BT + (size_t)(n0 + nr) * K + k0 + kc;
    *(uint4*)dst       = a;
    *(uint4*)(dst + 8) = b;
}

// ---------------- PASS 1: 256x256 bulk GEMM, counted vmcnt ----------------
__global__ __launch_bounds__(512, 2)
void bulk_mfma_256(const ushort* __restrict__ A2,   // [M][2K] bf16
                   const ushort* __restrict__ BT,   // [N][K]  bf16
                   float* __restrict__ O,
                   uint* __restrict__ flags, uint cap,
                   int M, int N, int K)
{
    __shared__ __align__(16) char lds[131072];  // 2 bufs x (A 32KB + B 32KB)

    const int tid = threadIdx.x;
    const int l   = tid & 63;
    const int wid = tid >> 6;          // 0..7
    const int wm  = wid >> 2;          // 0..1 (M wave)
    const int wn  = wid & 3;           // 0..3 (N wave)
    const int lr  = l & 15;
    const int lk  = l >> 4;

    // bijective XCD swizzle (nwg % 8 == 0)
    const int nwg = gridDim.x;
    int wg = blockIdx.x;
    wg = (wg & 7) * (nwg >> 3) + (wg >> 3);
    const int nbx = N >> 8;            // N/256
    const int m0 = (wg / nbx) << 8;
    const int n0 = (wg % nbx) << 8;

    const int NTr = K >> 6;            // real k-tiles (32)
    const int NTv = 2 * NTr;           // virtual (64)
    const size_t rowA = (size_t)(2 * K) * 2;   // bytes per A2 row
    const size_t rowB = (size_t)K * 2;         // bytes per BT row
    const char* A2b = (const char*)A2;
    const char* BTb = (const char*)BT;

    f32x4 acc[8][4];
    #pragma unroll
    for (int i = 0; i < 8; ++i)
        #pragma unroll
        for (int j = 0; j < 4; ++j)
            acc[i][j] = (f32x4){0.f, 0.f, 0.f, 0.f};

    // stage one K-tile (A 32KB + B 32KB) into buffer `buf`: 8 loads/wave
    auto STAGE = [&](int buf, int kt) {
        const size_t kA = (size_t)kt << 7;              // kt*128 bytes
        const size_t kB = (size_t)(kt % NTr) << 7;
        char* base = lds + buf * 65536;
        #pragma unroll
        for (int h = 0; h < 4; ++h) {
            const int chunk = wid * 4 + h;              // 0..31
            const int row = (chunk << 3) + (l >> 3);    // per-lane (source only)
            const int b   = (l & 7) << 4;
            const int bs  = b ^ ((row & 7) << 4);       // inverse swizzle on SRC
            const char* srcA = A2b + (size_t)(m0 + row) * rowA + kA + bs;
            char* dstA = base + chunk * 1024;           // wave-uniform dest
            __builtin_amdgcn_global_load_lds(
                (const __attribute__((address_space(1))) void*)srcA,
                (__attribute__((address_space(3))) void*)dstA, 16, 0, 0);
            const char* srcB = BTb + (size_t)(n0 + row) * rowB + kB + bs;
            char* dstB = base + 32768 + chunk * 1024;
            __builtin_amdgcn_global_load_lds(
                (const __attribute__((address_space(1))) void*)srcB,
                (__attribute__((address_space(3))) void*)dstB, 16, 0, 0);
        }
    };

    // compute one K-tile from buffer `buf`: 24 ds_read_b128 + 64 MFMA / wave
    auto COMPUTE = [&](int buf) {
        const char* sA = lds + buf * 65536;
        const char* sB = sA + 32768;
        #pragma unroll
        for (int ks = 0; ks < 2; ++ks) {
            const int kb = ks * 64 + lk * 16;
            bf16x8 af[8], bg[4];
            #pragma unroll
            for (int i = 0; i < 8; ++i) {
                const int row = wm * 128 + i * 16 + lr;
                af[i] = *(const bf16x8*)(sA + row * 128 + (kb ^ ((row & 7) << 4)));
            }
            #pragma unroll
            for (int j = 0; j < 4; ++j) {
                const int row = wn * 64 + j * 16 + lr;
                bg[j] = *(const bf16x8*)(sB + row * 128 + (kb ^ ((row & 7) << 4)));
            }
            #pragma unroll
            for (int i = 0; i < 8; ++i)
                #pragma unroll
                for (int j = 0; j < 4; ++j)
                    acc[i][j] = __builtin_amdgcn_mfma_f32_16x16x32_bf16(
                        af[i], bg[j], acc[i][j], 0, 0, 0);
        }
    };

    // prologue: tiles 0,1 in flight (16 loads/wave outstanding)
    STAGE(0, 0);
    STAGE(1, 1);

    for (int t = 0; t < NTv - 1; ++t) {
        // drain exactly tile t's 8 loads (tile t+1's 8 stay in flight)
        asm volatile("s_waitcnt vmcnt(8)" ::: "memory");
        __builtin_amdgcn_s_barrier();           // tile t globally complete
        __builtin_amdgcn_sched_barrier(0);
        COMPUTE(t & 1);
        __builtin_amdgcn_s_barrier();           // all waves done reading buf
        __builtin_amdgcn_sched_barrier(0);
        if (t + 2 < NTv) STAGE(t & 1, t + 2);   // refill vacated buffer
    }
    // peeled last tile
    asm volatile("s_waitcnt vmcnt(0)" ::: "memory");
    __builtin_amdgcn_s_barrier();
    __builtin_amdgcn_sched_barrier(0);
    COMPUTE((NTv - 1) & 1);

    // epilogue: sign + borderline flagging (C/D: col=lane&15, row=lk*4+q)
    #pragma unroll
    for (int i = 0; i < 8; ++i) {
        #pragma unroll
        for (int j = 0; j < 4; ++j) {
            #pragma unroll
            for (int q = 0; q < 4; ++q) {
                const int m = m0 + wm * 128 + i * 16 + lk * 4 + q;
                const int n = n0 + wn * 64 + j * 16 + lr;
                const float d = acc[i][j][q];
                const size_t oi = (size_t)m * N + n;
                O[oi] = sgnf(d);
                if (fabsf(d) < TAU) {
                    const uint pos = atomicAdd(flags, 1u);
                    if (pos < cap) flags[1 + pos] = (uint)oi;
                }
            }
        }
    }
}

// ---------------- FALLBACK bulk (R12-certified, fused conversion) ----------
__global__ __launch_bounds__(256, 2)
void bulk_mfma_fb(const float* __restrict__ X, const float* __restrict__ W,
                  float* __restrict__ O, uint* __restrict__ flags,
                  uint cap, int M, int N, int K)
{
    __shared__ __align__(16) char sA[128 * 128];
    __shared__ __align__(16) char sB[128 * 128];

    const int tid = threadIdx.x;
    const int l   = tid & 63;
    const int w   = tid >> 6;
    const int wr  = w >> 1, wc = w & 1;
    const int lr  = l & 15;
    const int lk  = l >> 4;

    const int m0 = blockIdx.y * 128;
    const int n0 = blockIdx.x * 128;

    f32x4 acc[4][4];
    #pragma unroll
    for (int i = 0; i < 4; ++i)
        #pragma unroll
        for (int j = 0; j < 4; ++j)
            acc[i][j] = (f32x4){0.f, 0.f, 0.f, 0.f};

    const int NT = K / 64;

    for (int kt = 0; kt < 2 * NT; ++kt) {
        const int plane = (kt >= NT);
        const int kr0 = (plane ? (kt - NT) : kt) * 64;

        #pragma unroll
        for (int h = 0; h < 4; ++h) {
            const int idx = tid + 256 * h;
            const int r   = idx >> 3;
            const int c8  = (idx & 7) * 8;
            const float* xp = &X[(size_t)(m0 + r) * K + kr0 + c8];
            const float4 v0 = *(const float4*)xp;
            const float4 v1 = *(const float4*)(xp + 4);
            const float xs[8] = {v0.x, v0.y, v0.z, v0.w, v1.x, v1.y, v1.z, v1.w};
            ushort hb[8];
            if (!plane) {
                #pragma unroll
                for (int e = 0; e < 8; ++e) hb[e] = f2bf(xs[e]);
            } else {
                #pragma unroll
                for (int e = 0; e < 8; ++e) {
                    const ushort h1 = f2bf(xs[e]);
                    hb[e] = f2bf(xs[e] - bf2f(h1));
                }
            }
            uint4 pk;
            pk.x = (uint)hb[0] | ((uint)hb[1] << 16);
            pk.y = (uint)hb[2] | ((uint)hb[3] << 16);
            pk.z = (uint)hb[4] | ((uint)hb[5] << 16);
            pk.w = (uint)hb[6] | ((uint)hb[7] << 16);
            *(uint4*)(sA + r * 128 + ((c8 * 2) ^ ((r & 7) << 4))) = pk;
        }
        {
            const int ko = (tid >> 5) * 8;
            const int n4 = (tid & 31) * 4;
            float4 rv[8];
            #pragma unroll
            for (int j = 0; j < 8; ++j)
                rv[j] = *(const float4*)&W[(size_t)(kr0 + ko + j) * N + n0 + n4];
            #pragma unroll
            for (int c = 0; c < 4; ++c) {
                ushort sb[8];
                #pragma unroll
                for (int j = 0; j < 8; ++j)
                    sb[j] = sgnbf(((const float*)&rv[j])[c]);
                uint4 pk;
                pk.x = (uint)sb[0] | ((uint)sb[1] << 16);
                pk.y = (uint)sb[2] | ((uint)sb[3] << 16);
                pk.z = (uint)sb[4] | ((uint)sb[5] << 16);
                pk.w = (uint)sb[6] | ((uint)sb[7] << 16);
                const int row = n4 + c;
                *(uint4*)(sB + row * 128 + ((ko * 2) ^ ((row & 7) << 4))) = pk;
            }
        }
        __syncthreads();

        #pragma unroll
        for (int kk = 0; kk < 2; ++kk) {
            const int kb = kk * 64 + lk * 16;
            bf16x8 af[4], bg[4];
            #pragma unroll
            for (int i = 0; i < 4; ++i) {
                const int row = wr * 64 + i * 16 + lr;
                af[i] = *(const bf16x8*)(sA + row * 128 + (kb ^ ((row & 7) << 4)));
            }
            #pragma unroll
            for (int j = 0; j < 4; ++j) {
                const int row = wc * 64 + j * 16 + lr;
                bg[j] = *(const bf16x8*)(sB + row * 128 + (kb ^ ((row & 7) << 4)));
            }
            #pragma unroll
            for (int i = 0; i < 4; ++i)
                #pragma unroll
                for (int j = 0; j < 4; ++j)
                    acc[i][j] = __builtin_amdgcn_mfma_f32_16x16x32_bf16(
                        af[i], bg[j], acc[i][j], 0, 0, 0);
        }
        __syncthreads();
    }

    #pragma unroll
    for (int i = 0; i < 4; ++i) {
        #pragma unroll
        for (int j = 0; j < 4; ++j) {
            #pragma unroll
            for (int q = 0; q < 4; ++q) {
                const int m = m0 + wr * 64 + i * 16 + lk * 4 + q;
                const int n = n0 + wc * 64 + j * 16 + lr;
                const float d = acc[i][j][q];
                const size_t oi = (size_t)m * N + n;
                O[oi] = sgnf(d);
                if (fabsf(d) < TAU) {
                    const uint pos = atomicAdd(flags, 1u);
                    if (pos < cap) flags[1 + pos] = (uint)oi;
                }
            }
        }
    }
}

// ---------------- PASS 2: fixup reading BT (coalesced) ----------------
__global__ __launch_bounds__(64)
void fixup_exact_bt(const float* __restrict__ X, const ushort* __restrict__ BT,
                    float* __restrict__ O, const uint* __restrict__ flags,
                    uint cap, int K, int N)
{
    __shared__ float p[2048];

    uint count = flags[0];
    if (count > cap) count = cap;

    for (uint t = blockIdx.x; t < count; t += gridDim.x) {
        const uint idx = flags[1 + t];
        const int n = (int)(idx % (uint)N);
        const float* xrow = X + (size_t)(idx / (uint)N) * K;
        const ushort* brow = BT + (size_t)n * K;

        for (int k = threadIdx.x; k < K; k += 64)
            p[k] = xrow[k] * bf2f(brow[k]);     // exact +-x products
        __syncthreads();
        if (threadIdx.x == 0) {
            float sum = 0.f;
            int ls = 0;
            while (ls < K) {                     // HD panels [384x5,128]
                const int ke = (ls + 384 < K) ? (ls + 384) : K;
                float part = 0.f;
                for (int k = ls; k < ke; ++k) part += p[k];
                sum += part;
                ls = ke;
            }
            O[idx] = sgnf(sum);
        }
        __syncthreads();
    }
}

// ---------------- fallback fixup (reads W columns) ----------------
__global__ __launch_bounds__(64)
void fixup_exact_wave(const float* __restrict__ X, const float* __restrict__ W,
                      float* __restrict__ O, const uint* __restrict__ flags,
                      uint cap, int K, int N)
{
    __shared__ float p[2048];

    uint count = flags[0];
    if (count > cap) count = cap;

    for (uint t = blockIdx.x; t < count; t += gridDim.x) {
        const uint idx = flags[1 + t];
        const int n = (int)(idx % (uint)N);
        const float* xrow = X + (size_t)(idx / (uint)N) * K;
        const float* wcol = W + n;

        if (K <= 2048) {
            for (int k = threadIdx.x; k < K; k += 64)
                p[k] = xrow[k] * sgnf(wcol[(size_t)k * N]);
            __syncthreads();
            if (threadIdx.x == 0) {
                float sum = 0.f;
                int ls = 0;
                while (ls < K) {
                    const int ke = (ls + 384 < K) ? (ls + 384) : K;
                    float part = 0.f;
                    for (int k = ls; k < ke; ++k) part += p[k];
                    sum += part;
                    ls = ke;
                }
                O[idx] = sgnf(sum);
            }
            __syncthreads();
        } else if (threadIdx.x == 0) {
            float sum = 0.f;
            int ls = 0;
            while (ls < K) {
                const int ke = (ls + 384 < K) ? (ls + 384) : K;
                float part = 0.f;
                for (int k = ls; k < ke; ++k)
                    part = fmaf(xrow[k], sgnf(wcol[(size_t)k * N]), part);
                sum += part;
                ls = ke;
            }
            O[idx] = sgnf(sum);
        }
    }
}

extern "C" void kernel_launch(void* const* d_in, const int* in_sizes, int n_in,
                              void* d_out, int out_size, void* d_ws, size_t ws_size,
                              hipStream_t stream) {
    // order-robust input binding (x = larger buffer)
    const float* X;
    const float* W;
    long long wsize;
    if ((long long)in_sizes[0] >= (long long)in_sizes[1]) {
        X = (const float*)d_in[0];
        W = (const float*)d_in[1]; wsize = in_sizes[1];
    } else {
        X = (const float*)d_in[1];
        W = (const float*)d_in[0]; wsize = in_sizes[0];
    }
    float* O = (float*)d_out;

    int K = 1;
    while ((long long)K * K < wsize) ++K;        // K = 2048
    const int N = K;
    const int M = (int)((long long)out_size / N);

    const size_t A2_BYTES = (size_t)M * 2 * K * 2;   // 64 MB
    const size_t BT_BYTES = (size_t)N * K * 2;       // 8 MB
    const size_t FLAG_OFF = A2_BYTES + BT_BYTES;
    const bool big_ws = (ws_size >= FLAG_OFF + (1u << 16)) &&
                        (M % 256 == 0) && (N % 256 == 0) &&
                        (K % 64 == 0) && (K <= 2048);

    if (big_ws) {
        ushort* A2 = (ushort*)d_ws;
        ushort* BT = (ushort*)((char*)d_ws + A2_BYTES);
        uint* flags = (uint*)((char*)d_ws + FLAG_OFF);
        unsigned long long c = (unsigned long long)((ws_size - FLAG_OFF) / 4) - 1ull;
        const uint cap = (uint)((c > 0x00FFFFFFull) ? 0x00FFFFFFull : c);

        conv_x_planes<<<(M * (K >> 3) + 255) / 256, 256, 0, stream>>>(X, A2, flags, M, K);
        dim3 tg(N / 64, K / 64);
        transp_sign<<<tg, 256, 0, stream>>>(W, BT, K, N);
        const int nwg = (N / 256) * (M / 256);       // 256, % 8 == 0
        bulk_mfma_256<<<nwg, 512, 0, stream>>>(A2, BT, O, flags, cap, M, N, K);
        fixup_exact_bt<<<2048, 64, 0, stream>>>(X, BT, O, flags, cap, K, N);
    } else {
        uint* flags = (uint*)d_ws;
        uint cap = 0;
        if (ws_size >= 8) {
            unsigned long long c = (unsigned long long)(ws_size / 4) - 1ull;
            cap = (uint)((c > 0x00FFFFFFull) ? 0x00FFFFFFull : c);
        }
        hipMemsetAsync(d_ws, 0, 4, stream);
        dim3 grid(N / 128, M / 128);
        bulk_mfma_fb<<<grid, 256, 0, stream>>>(X, W, O, flags, cap, M, N, K);
        fixup_exact_wave<<<2048, 64, 0, stream>>>(X, W, O, flags, cap, K, N);
    }
}